// Round 2
// baseline (1392.246 us; speedup 1.0000x reference)
//
#include <hip/hip_runtime.h>
#include <hip/hip_bf16.h>

#define N_NODES 50000
#define N_EDGES 800000
#define F_IN 512
#define HIDDEN 128
#define N_CLASSES 40

#define G1_KC 128      // K-chunk for W1 LDS staging: 128*128*4 = 64 KB
#define G1_NODES 16    // nodes per block in gemm1
#define G2_NODES 16    // nodes per block in gemm2

// ---------------- degree / norm ----------------
__global__ void deg_init_kernel(float* __restrict__ deg) {
    int i = blockIdx.x * 256 + threadIdx.x;
    if (i < N_NODES) deg[i] = 1.0f;  // self-loop contributes 1
}

__global__ void deg_count_kernel(const int* __restrict__ col, float* __restrict__ deg) {
    int i = blockIdx.x * 256 + threadIdx.x;
    if (i < N_EDGES) atomicAdd(&deg[col[i]], 1.0f);
}

__global__ void deg_fin_kernel(float* __restrict__ deg) {
    int i = blockIdx.x * 256 + threadIdx.x;
    if (i < N_NODES) deg[i] = rsqrtf(deg[i]);  // deg buffer becomes dinv
}

// ---------------- GEMM1: h1[N,128] = x[N,512] @ W1[512,128] ----------------
// 128 threads = 128 output features; 16 nodes per block; W1 chunk in LDS.
// x[] addresses are lane-uniform -> scalar loads; W read once per k, 16 FMAs.
__global__ __launch_bounds__(128) void gemm1_kernel(
    const float* __restrict__ x,
    const float* __restrict__ W1,
    float* __restrict__ h1)
{
    __shared__ float Wl[G1_KC * HIDDEN];  // 64 KB
    const int f     = threadIdx.x;        // 0..127
    const int node0 = blockIdx.x * G1_NODES;

    float acc[G1_NODES];
    #pragma unroll
    for (int n = 0; n < G1_NODES; ++n) acc[n] = 0.0f;

    for (int kc = 0; kc < F_IN; kc += G1_KC) {
        // stage W1 chunk into LDS (float4, coalesced): 16384 floats / 128 thr
        const float4* src = (const float4*)(W1 + kc * HIDDEN);
        float4* dst = (float4*)Wl;
        for (int i = threadIdx.x; i < (G1_KC * HIDDEN) / 4; i += 128)
            dst[i] = src[i];
        __syncthreads();

        #pragma unroll 4
        for (int k = 0; k < G1_KC; ++k) {
            const float w = Wl[k * HIDDEN + f];   // conflict-free (stride-1 over f)
            #pragma unroll
            for (int n = 0; n < G1_NODES; ++n)
                acc[n] = fmaf(x[(size_t)(node0 + n) * F_IN + kc + k], w, acc[n]);
        }
        __syncthreads();
    }

    #pragma unroll
    for (int n = 0; n < G1_NODES; ++n)
        h1[(node0 + n) * HIDDEN + f] = acc[n];
}

// ---------------- scatter1: agg1[row] += h1[col]*norm ----------------
__global__ __launch_bounds__(128) void scatter1_kernel(
    const int* __restrict__ row, const int* __restrict__ col,
    const float* __restrict__ dinv, const float* __restrict__ h1,
    float* __restrict__ agg1)
{
    const int e = blockIdx.x;
    const int r = row[e], c = col[e];
    const float nrm = dinv[r] * dinv[c];
    const int f = threadIdx.x;
    atomicAdd(&agg1[r * HIDDEN + f], h1[c * HIDDEN + f] * nrm);
}

// ---------------- post1: agg1 = relu(agg1 + selfloop + b1) ----------------
__global__ void post1_kernel(const float* __restrict__ h1, const float* __restrict__ dinv,
                             const float* __restrict__ b1, float* __restrict__ agg1)
{
    int idx = blockIdx.x * 256 + threadIdx.x;
    if (idx >= N_NODES * HIDDEN) return;
    int node = idx >> 7;
    int f    = idx & (HIDDEN - 1);
    float dv = dinv[node];
    float v  = agg1[idx] + h1[idx] * dv * dv + b1[f];
    agg1[idx] = fmaxf(v, 0.0f);
}

// ---------------- GEMM2: h2[N,40] = agg1[N,128] @ W2[128,40] ----------------
// 64 threads (40 active for output), 16 nodes/block, W2 fully in LDS.
__global__ __launch_bounds__(64) void gemm2_kernel(
    const float* __restrict__ hin,
    const float* __restrict__ W2,
    float* __restrict__ h2)
{
    __shared__ float Wl2[HIDDEN * N_CLASSES];  // 20480 B
    const int f     = threadIdx.x;             // 0..63, active f<40
    const int node0 = blockIdx.x * G2_NODES;

    for (int i = threadIdx.x; i < HIDDEN * N_CLASSES; i += 64)
        Wl2[i] = W2[i];
    __syncthreads();

    float acc[G2_NODES];
    #pragma unroll
    for (int n = 0; n < G2_NODES; ++n) acc[n] = 0.0f;

    #pragma unroll 4
    for (int k = 0; k < HIDDEN; ++k) {
        const float w = (f < N_CLASSES) ? Wl2[k * N_CLASSES + f] : 0.0f;
        #pragma unroll
        for (int n = 0; n < G2_NODES; ++n)
            acc[n] = fmaf(hin[(node0 + n) * HIDDEN + k], w, acc[n]);
    }

    if (f < N_CLASSES) {
        #pragma unroll
        for (int n = 0; n < G2_NODES; ++n)
            h2[(node0 + n) * N_CLASSES + f] = acc[n];
    }
}

// ---------------- scatter2: agg2[row] += h2[col]*norm ----------------
__global__ void scatter2_kernel(const int* __restrict__ row, const int* __restrict__ col,
                                const float* __restrict__ dinv, const float* __restrict__ h2,
                                float* __restrict__ agg2)
{
    int idx = blockIdx.x * 256 + threadIdx.x;
    if (idx >= N_EDGES * N_CLASSES) return;
    int e = idx / N_CLASSES;
    int f = idx - e * N_CLASSES;
    int r = row[e], c = col[e];
    float nrm = dinv[r] * dinv[c];
    atomicAdd(&agg2[r * N_CLASSES + f], h2[c * N_CLASSES + f] * nrm);
}

// ---------------- post2: out = agg2 + selfloop + b2 ----------------
__global__ void post2_kernel(const float* __restrict__ h2, const float* __restrict__ dinv,
                             const float* __restrict__ b2,
                             const float* __restrict__ agg2,
                             float* __restrict__ out)
{
    int idx = blockIdx.x * 256 + threadIdx.x;
    if (idx >= N_NODES * N_CLASSES) return;
    int node = idx / N_CLASSES;
    int f    = idx - node * N_CLASSES;
    float dv = dinv[node];
    out[idx] = agg2[idx] + h2[idx] * dv * dv + b2[f];
}

extern "C" void kernel_launch(void* const* d_in, const int* in_sizes, int n_in,
                              void* d_out, int out_size, void* d_ws, size_t ws_size,
                              hipStream_t stream)
{
    const float* x  = (const float*)d_in[0];
    const int*   ei = (const int*)d_in[1];
    const float* W1 = (const float*)d_in[2];
    const float* b1 = (const float*)d_in[3];
    const float* W2 = (const float*)d_in[4];
    const float* b2 = (const float*)d_in[5];
    const int* row = ei;            // destinations (out[row] += ...)
    const int* col = ei + N_EDGES;  // sources (gather h[col])

    float* ws   = (float*)d_ws;
    float* dinv = ws;                                   // 50000 f32 (deg -> dinv)
    float* h1   = ws + 65536;                           // 50000*128 f32
    float* agg1 = h1 + (size_t)N_NODES * HIDDEN;        // 50000*128 f32
    // h1 is dead after post1 -> alias layer-2 buffers into its region
    float* h2   = h1;                                   // 50000*40 f32
    float* agg2 = h1 + (size_t)N_NODES * N_CLASSES;     // 50000*40 f32
    float* out  = (float*)d_out;

    deg_init_kernel<<<(N_NODES + 255) / 256, 256, 0, stream>>>(dinv);
    deg_count_kernel<<<(N_EDGES + 255) / 256, 256, 0, stream>>>(col, dinv);
    deg_fin_kernel<<<(N_NODES + 255) / 256, 256, 0, stream>>>(dinv);

    gemm1_kernel<<<N_NODES / G1_NODES, 128, 0, stream>>>(x, W1, h1);

    hipMemsetAsync(agg1, 0, (size_t)N_NODES * HIDDEN * sizeof(float), stream);
    scatter1_kernel<<<N_EDGES, 128, 0, stream>>>(row, col, dinv, h1, agg1);
    post1_kernel<<<(N_NODES * HIDDEN + 255) / 256, 256, 0, stream>>>(h1, dinv, b1, agg1);

    gemm2_kernel<<<N_NODES / G2_NODES, 64, 0, stream>>>(agg1, W2, h2);

    hipMemsetAsync(agg2, 0, (size_t)N_NODES * N_CLASSES * sizeof(float), stream);
    scatter2_kernel<<<((size_t)N_EDGES * N_CLASSES + 255) / 256, 256, 0, stream>>>(row, col, dinv, h2, agg2);
    post2_kernel<<<(N_NODES * N_CLASSES + 255) / 256, 256, 0, stream>>>(h2, dinv, b2, agg2, out);
}

// Round 3
// 519.081 us; speedup vs baseline: 2.6821x; 2.6821x over previous
//
#include <hip/hip_runtime.h>
#include <hip/hip_bf16.h>

#define N_NODES 50000
#define N_EDGES 800000
#define F_IN 512
#define HIDDEN 128
#define N_CLASSES 40

#define BM 128       // gemm1 node-tile
#define KC 32        // gemm1 k-chunk
#define NSCAN 196    // ceil(50000/256)

// ---------------- init: deg=1 (self-loop), rowcnt=0, cursor=0 ----------------
__global__ void init_kernel(float* __restrict__ deg, int* __restrict__ rowcnt,
                            int* __restrict__ cursor) {
    int i = blockIdx.x * 256 + threadIdx.x;
    if (i < N_NODES) { deg[i] = 1.0f; rowcnt[i] = 0; cursor[i] = 0; }
}

// deg over col (normalization) + rowcnt over row (CSR histogram)
__global__ void count_kernel(const int* __restrict__ row, const int* __restrict__ col,
                             float* __restrict__ deg, int* __restrict__ rowcnt) {
    int e = blockIdx.x * 256 + threadIdx.x;
    if (e < N_EDGES) {
        atomicAdd(&deg[col[e]], 1.0f);
        atomicAdd(&rowcnt[row[e]], 1);
    }
}

__global__ void deg_fin_kernel(float* __restrict__ deg) {
    int i = blockIdx.x * 256 + threadIdx.x;
    if (i < N_NODES) deg[i] = rsqrtf(deg[i]);  // deg buffer becomes dinv
}

// ---------------- exclusive scan of rowcnt -> rowptr ----------------
__global__ void scan_blocks_kernel(const int* __restrict__ rowcnt, int* __restrict__ rowptr,
                                   int* __restrict__ partials) {
    __shared__ int s[256];
    const int tid = threadIdx.x;
    const int i = blockIdx.x * 256 + tid;
    const int v = (i < N_NODES) ? rowcnt[i] : 0;
    s[tid] = v;
    __syncthreads();
    #pragma unroll
    for (int off = 1; off < 256; off <<= 1) {
        int t = (tid >= off) ? s[tid - off] : 0;
        __syncthreads();
        s[tid] += t;
        __syncthreads();
    }
    if (i < N_NODES) rowptr[i] = s[tid] - v;      // exclusive within block
    if (tid == 255) partials[blockIdx.x] = s[255]; // block total
}

__global__ void scan_partials_kernel(int* __restrict__ partials) {
    __shared__ int s[256];
    const int tid = threadIdx.x;
    const int v = (tid < NSCAN) ? partials[tid] : 0;
    s[tid] = v;
    __syncthreads();
    #pragma unroll
    for (int off = 1; off < 256; off <<= 1) {
        int t = (tid >= off) ? s[tid - off] : 0;
        __syncthreads();
        s[tid] += t;
        __syncthreads();
    }
    if (tid < NSCAN) partials[tid] = s[tid] - v;  // exclusive
}

__global__ void scan_add_kernel(int* __restrict__ rowptr, const int* __restrict__ partials) {
    int i = blockIdx.x * 256 + threadIdx.x;
    if (i < N_NODES) rowptr[i] += partials[blockIdx.x];
    if (i == 0) rowptr[N_NODES] = N_EDGES;
}

// ---------------- CSR placement: ecol sorted by row ----------------
__global__ void place_kernel(const int* __restrict__ row, const int* __restrict__ col,
                             const int* __restrict__ rowptr, int* __restrict__ cursor,
                             int* __restrict__ ecol) {
    int e = blockIdx.x * 256 + threadIdx.x;
    if (e < N_EDGES) {
        int r = row[e];
        int pos = rowptr[r] + atomicAdd(&cursor[r], 1);
        ecol[pos] = col[e];
    }
}

// ---------------- GEMM1: h1s[N,128] = (x[N,512] @ W1[512,128]) * dinv[row] ----
// 256 thr, 128x128 tile, KC=32, 8x8 register tile per thread.
__global__ __launch_bounds__(256) void gemm1_kernel(
    const float* __restrict__ x, const float* __restrict__ W1,
    const float* __restrict__ dinv, float* __restrict__ h1s)
{
    __shared__ float XT[KC][BM];      // transposed x tile, 16 KB
    __shared__ float Ws[KC][HIDDEN];  // 16 KB
    const int tid  = threadIdx.x;
    const int tn   = tid & 15;        // 0..15 -> 8-col group
    const int tm   = tid >> 4;        // 0..15 -> 8-row group
    const int row0 = blockIdx.x * BM;
    const int lr   = tid & 127;       // staging row
    const int half = tid >> 7;        // staging k-half (0/1)

    float acc[8][8] = {};

    for (int kc = 0; kc < F_IN; kc += KC) {
        // stage x tile: each thread loads 64B contiguous (16 floats of one row)
        {
            float4 v[4] = {};
            const int grow = row0 + lr;
            if (grow < N_NODES) {
                const float4* p = (const float4*)(x + (size_t)grow * F_IN + kc + half * 16);
                v[0] = p[0]; v[1] = p[1]; v[2] = p[2]; v[3] = p[3];
            }
            #pragma unroll
            for (int q = 0; q < 4; ++q) {
                XT[half*16 + q*4 + 0][lr] = v[q].x;
                XT[half*16 + q*4 + 1][lr] = v[q].y;
                XT[half*16 + q*4 + 2][lr] = v[q].z;
                XT[half*16 + q*4 + 3][lr] = v[q].w;
            }
        }
        // stage W tile: 4096 contiguous floats
        {
            const float4* src = (const float4*)(W1 + (size_t)kc * HIDDEN);
            float4* dst = (float4*)&Ws[0][0];
            #pragma unroll
            for (int q = 0; q < 4; ++q) dst[tid + q*256] = src[tid + q*256];
        }
        __syncthreads();

        #pragma unroll
        for (int k = 0; k < KC; ++k) {
            float a[8], b[8];
            *(float4*)&a[0] = *(const float4*)&XT[k][tm*8];
            *(float4*)&a[4] = *(const float4*)&XT[k][tm*8 + 4];
            *(float4*)&b[0] = *(const float4*)&Ws[k][tn*8];
            *(float4*)&b[4] = *(const float4*)&Ws[k][tn*8 + 4];
            #pragma unroll
            for (int i = 0; i < 8; ++i)
                #pragma unroll
                for (int j = 0; j < 8; ++j)
                    acc[i][j] = fmaf(a[i], b[j], acc[i][j]);
        }
        __syncthreads();
    }

    #pragma unroll
    for (int i = 0; i < 8; ++i) {
        const int r = row0 + tm*8 + i;
        if (r < N_NODES) {
            const float s = dinv[r];
            float* dst = h1s + (size_t)r * HIDDEN + tn*8;
            float4 o;
            o.x = acc[i][0]*s; o.y = acc[i][1]*s; o.z = acc[i][2]*s; o.w = acc[i][3]*s;
            ((float4*)dst)[0] = o;
            o.x = acc[i][4]*s; o.y = acc[i][5]*s; o.z = acc[i][6]*s; o.w = acc[i][7]*s;
            ((float4*)dst)[1] = o;
        }
    }
}

// ---------------- gather1: agg1[r] = relu(dinv[r]*(sum h1s[c] + h1s[r]) + b1) --
// one wave per node; lane holds 2 of 128 features; 2-edge unroll.
__global__ __launch_bounds__(256) void gather1_kernel(
    const int* __restrict__ rowptr, const int* __restrict__ ecol,
    const float* __restrict__ dinv, const float* __restrict__ h1s,
    const float* __restrict__ b1, float* __restrict__ agg1)
{
    const int wave = threadIdx.x >> 6;
    const int lane = threadIdx.x & 63;
    const int r = blockIdx.x * 4 + wave;
    if (r >= N_NODES) return;
    const int start = rowptr[r], end = rowptr[r + 1];

    float ax0 = 0.f, ay0 = 0.f, ax1 = 0.f, ay1 = 0.f;
    int e = start;
    for (; e + 1 < end; e += 2) {
        const int c0 = ecol[e], c1 = ecol[e + 1];
        const float2 v0 = *(const float2*)&h1s[(size_t)c0 * HIDDEN + lane * 2];
        const float2 v1 = *(const float2*)&h1s[(size_t)c1 * HIDDEN + lane * 2];
        ax0 += v0.x; ay0 += v0.y;
        ax1 += v1.x; ay1 += v1.y;
    }
    if (e < end) {
        const int c = ecol[e];
        const float2 v = *(const float2*)&h1s[(size_t)c * HIDDEN + lane * 2];
        ax0 += v.x; ay0 += v.y;
    }
    const float2 self = *(const float2*)&h1s[(size_t)r * HIDDEN + lane * 2];
    const float2 bb = *(const float2*)&b1[lane * 2];
    const float s = dinv[r];
    float2 o;
    o.x = fmaxf(fmaf(s, ax0 + ax1 + self.x, bb.x), 0.f);
    o.y = fmaxf(fmaf(s, ay0 + ay1 + self.y, bb.y), 0.f);
    *(float2*)&agg1[(size_t)r * HIDDEN + lane * 2] = o;
}

// ---------------- GEMM2: h2s[N,40] = (agg1[N,128] @ W2[128,40]) * dinv[row] ---
// 4 nodes/block (one wave each); W2 + 4 agg1 rows staged in LDS.
__global__ __launch_bounds__(256) void gemm2_kernel(
    const float* __restrict__ agg1, const float* __restrict__ W2,
    const float* __restrict__ dinv, float* __restrict__ h2s)
{
    __shared__ float W2l[HIDDEN * N_CLASSES];  // 20480 B
    __shared__ float rows[4][HIDDEN];          // 2 KB
    const int tid = threadIdx.x;
    const int node0 = blockIdx.x * 4;

    {   // copy W2 (5120 floats = 1280 float4)
        const float4* src = (const float4*)W2;
        float4* dst = (float4*)W2l;
        #pragma unroll
        for (int q = 0; q < 5; ++q) dst[tid + q*256] = src[tid + q*256];
    }
    {   // stage 4 rows of agg1 (512 floats): float2 per thread
        const int i = tid * 2;
        const int w = i >> 7, kk = i & 127;
        *(float2*)&rows[w][kk] = *(const float2*)&agg1[(size_t)(node0 + w) * HIDDEN + kk];
    }
    __syncthreads();

    const int wave = tid >> 6, lane = tid & 63;
    if (lane >= N_CLASSES) return;
    const int r = node0 + wave;
    float acc = 0.f;
    #pragma unroll 8
    for (int k = 0; k < HIDDEN; ++k)
        acc = fmaf(rows[wave][k], W2l[k * N_CLASSES + lane], acc);
    h2s[(size_t)r * N_CLASSES + lane] = acc * dinv[r];
}

// ---------------- gather2: out[r] = dinv[r]*(sum h2s[c] + h2s[r]) + b2 -------
__global__ __launch_bounds__(256) void gather2_kernel(
    const int* __restrict__ rowptr, const int* __restrict__ ecol,
    const float* __restrict__ dinv, const float* __restrict__ h2s,
    const float* __restrict__ b2, float* __restrict__ out)
{
    const int wave = threadIdx.x >> 6;
    const int lane = threadIdx.x & 63;
    const int r = blockIdx.x * 4 + wave;
    if (r >= N_NODES || lane >= N_CLASSES) return;
    const int start = rowptr[r], end = rowptr[r + 1];

    float a0 = 0.f, a1 = 0.f;
    int e = start;
    for (; e + 1 < end; e += 2) {
        const int c0 = ecol[e], c1 = ecol[e + 1];
        a0 += h2s[(size_t)c0 * N_CLASSES + lane];
        a1 += h2s[(size_t)c1 * N_CLASSES + lane];
    }
    if (e < end) a0 += h2s[(size_t)ecol[e] * N_CLASSES + lane];
    const float self = h2s[(size_t)r * N_CLASSES + lane];
    out[(size_t)r * N_CLASSES + lane] = fmaf(dinv[r], a0 + a1 + self, b2[lane]);
}

extern "C" void kernel_launch(void* const* d_in, const int* in_sizes, int n_in,
                              void* d_out, int out_size, void* d_ws, size_t ws_size,
                              hipStream_t stream)
{
    const float* x  = (const float*)d_in[0];
    const int*   ei = (const int*)d_in[1];
    const float* W1 = (const float*)d_in[2];
    const float* b1 = (const float*)d_in[3];
    const float* W2 = (const float*)d_in[4];
    const float* b2 = (const float*)d_in[5];
    const int* row = ei;            // destinations (out[row] += ...)
    const int* col = ei + N_EDGES;  // sources (gather h[col])

    float* ws = (float*)d_ws;
    float* dinv     = ws;                      // [0,       65536)
    int*   rowptr   = (int*)(ws + 65536);      // 50001    -> 65536 slots
    int*   cursor   = (int*)(ws + 131072);     // 50000    -> 65536
    int*   rowcnt   = (int*)(ws + 196608);     // 50000    -> 65536
    int*   partials = (int*)(ws + 262144);     // 256      -> 8192
    int*   ecol     = (int*)(ws + 270336);     // 800000   -> 819200
    float* h1s      = ws + 1089536;            // 6,400,000
    float* agg1     = ws + 7489536;            // 6,400,000  (top ~55.6 MB)
    float* h2s      = h1s;                     // alias: h1s dead after gather1
    float* out      = (float*)d_out;

    init_kernel<<<(N_NODES + 255) / 256, 256, 0, stream>>>(dinv, rowcnt, cursor);
    count_kernel<<<(N_EDGES + 255) / 256, 256, 0, stream>>>(row, col, dinv, rowcnt);
    deg_fin_kernel<<<(N_NODES + 255) / 256, 256, 0, stream>>>(dinv);

    scan_blocks_kernel<<<NSCAN, 256, 0, stream>>>(rowcnt, rowptr, partials);
    scan_partials_kernel<<<1, 256, 0, stream>>>(partials);
    scan_add_kernel<<<NSCAN, 256, 0, stream>>>(rowptr, partials);
    place_kernel<<<(N_EDGES + 255) / 256, 256, 0, stream>>>(row, col, rowptr, cursor, ecol);

    gemm1_kernel<<<(N_NODES + BM - 1) / BM, 256, 0, stream>>>(x, W1, dinv, h1s);
    gather1_kernel<<<N_NODES / 4, 256, 0, stream>>>(rowptr, ecol, dinv, h1s, b1, agg1);
    gemm2_kernel<<<N_NODES / 4, 256, 0, stream>>>(agg1, W2, dinv, h2s);
    gather2_kernel<<<N_NODES / 4, 256, 0, stream>>>(rowptr, ecol, dinv, h2s, b2, out);
}

// Round 4
// 385.325 us; speedup vs baseline: 3.6132x; 1.3471x over previous
//
#include <hip/hip_runtime.h>
#include <hip/hip_bf16.h>

#define N_NODES 50000
#define N_EDGES 800000
#define F_IN 512
#define HIDDEN 128
#define N_CLASSES 40
#define NSCAN 196    // ceil(50000/256)

typedef __attribute__((ext_vector_type(4))) float f32x4;
typedef __attribute__((ext_vector_type(8))) short s16x8;

// manual RNE f32 -> bf16 (matches hardware cvt for normals)
__device__ __forceinline__ unsigned bf16r(float f) {
    unsigned u = __float_as_uint(f);
    return (u + 0x7fffu + ((u >> 16) & 1u)) >> 16;
}
__device__ __forceinline__ unsigned pkbf(float lo, float hi) {
    return bf16r(lo) | (bf16r(hi) << 16);
}
__device__ __forceinline__ float bflo(unsigned u) { return __uint_as_float(u << 16); }
__device__ __forceinline__ float bfhi(unsigned u) { return __uint_as_float(u & 0xffff0000u); }

// ---------------- init: counters = 0 ----------------
__global__ void init_kernel(int* __restrict__ rowcnt, int* __restrict__ colcnt,
                            int* __restrict__ cursor) {
    int i = blockIdx.x * 256 + threadIdx.x;
    if (i < N_NODES) { rowcnt[i] = 0; colcnt[i] = 0; cursor[i] = 0; }
}

__global__ void count_kernel(const int* __restrict__ row, const int* __restrict__ col,
                             int* __restrict__ rowcnt, int* __restrict__ colcnt) {
    int e = blockIdx.x * 256 + threadIdx.x;
    if (e < N_EDGES) {
        atomicAdd(&rowcnt[row[e]], 1);
        atomicAdd(&colcnt[col[e]], 1);
    }
}

__global__ void deg_fin_kernel(const int* __restrict__ colcnt, float* __restrict__ dinv) {
    int i = blockIdx.x * 256 + threadIdx.x;
    if (i < N_NODES) dinv[i] = rsqrtf(1.0f + (float)colcnt[i]);  // +1 self-loop
}

// ---------------- exclusive scan of rowcnt -> rowptr ----------------
__global__ void scan_blocks_kernel(const int* __restrict__ rowcnt, int* __restrict__ rowptr,
                                   int* __restrict__ partials) {
    __shared__ int s[256];
    const int tid = threadIdx.x;
    const int i = blockIdx.x * 256 + tid;
    const int v = (i < N_NODES) ? rowcnt[i] : 0;
    s[tid] = v;
    __syncthreads();
    #pragma unroll
    for (int off = 1; off < 256; off <<= 1) {
        int t = (tid >= off) ? s[tid - off] : 0;
        __syncthreads();
        s[tid] += t;
        __syncthreads();
    }
    if (i < N_NODES) rowptr[i] = s[tid] - v;
    if (tid == 255) partials[blockIdx.x] = s[255];
}

__global__ void scan_partials_kernel(int* __restrict__ partials) {
    __shared__ int s[256];
    const int tid = threadIdx.x;
    const int v = (tid < NSCAN) ? partials[tid] : 0;
    s[tid] = v;
    __syncthreads();
    #pragma unroll
    for (int off = 1; off < 256; off <<= 1) {
        int t = (tid >= off) ? s[tid - off] : 0;
        __syncthreads();
        s[tid] += t;
        __syncthreads();
    }
    if (tid < NSCAN) partials[tid] = s[tid] - v;
}

__global__ void scan_add_kernel(int* __restrict__ rowptr, const int* __restrict__ partials) {
    int i = blockIdx.x * 256 + threadIdx.x;
    if (i < N_NODES) rowptr[i] += partials[blockIdx.x];
    if (i == 0) rowptr[N_NODES] = N_EDGES;
}

// ---------------- CSR placement ----------------
__global__ void place_kernel(const int* __restrict__ row, const int* __restrict__ col,
                             const int* __restrict__ rowptr, int* __restrict__ cursor,
                             int* __restrict__ ecol) {
    int e = blockIdx.x * 256 + threadIdx.x;
    if (e < N_EDGES) {
        int r = row[e];
        int pos = rowptr[r] + atomicAdd(&cursor[r], 1);
        ecol[pos] = col[e];
    }
}

// ---------------- pre-pack W1 into B-fragment layout (bf16) ----------------
// frag f = (chunk c)*8*64 + (n-tile u)*64 + lane; lane holds B[k=c*32+quad*8+j][n=u*16+l16]
__global__ void w1frag_kernel(const float* __restrict__ W1, uint4* __restrict__ w1f) {
    int f = blockIdx.x * 256 + threadIdx.x;  // 0..8191
    int lane = f & 63, u = (f >> 6) & 7, c = f >> 9;
    int k0 = c * 32 + ((lane >> 4) << 3), n = u * 16 + (lane & 15);
    float v[8];
    #pragma unroll
    for (int j = 0; j < 8; ++j) v[j] = W1[(size_t)(k0 + j) * HIDDEN + n];
    uint4 o;
    o.x = pkbf(v[0], v[1]); o.y = pkbf(v[2], v[3]);
    o.z = pkbf(v[4], v[5]); o.w = pkbf(v[6], v[7]);
    w1f[f] = o;
}

// W2 (128x40, pad n to 48): frag f = c*3*64 + u*64 + lane, c<4, u<3
__global__ void w2frag_kernel(const float* __restrict__ W2, uint4* __restrict__ w2f) {
    int f = blockIdx.x * 256 + threadIdx.x;  // 0..767
    if (f >= 768) return;
    int lane = f & 63, u = (f >> 6) % 3, c = f / 192;
    int k0 = c * 32 + ((lane >> 4) << 3), n = u * 16 + (lane & 15);
    float v[8];
    #pragma unroll
    for (int j = 0; j < 8; ++j)
        v[j] = (n < N_CLASSES) ? W2[(size_t)(k0 + j) * N_CLASSES + n] : 0.0f;
    uint4 o;
    o.x = pkbf(v[0], v[1]); o.y = pkbf(v[2], v[3]);
    o.z = pkbf(v[4], v[5]); o.w = pkbf(v[6], v[7]);
    w2f[f] = o;
}

// ---------------- GEMM1 (MFMA): h1s[N,128]bf16 = (x @ W1) * dinv[row] ------
// block = 64 nodes x 128 feats, 4 waves; wave w owns n-columns [w*32, w*32+32)
__global__ __launch_bounds__(256) void gemm1_kernel(
    const float* __restrict__ x, const uint4* __restrict__ w1f,
    const float* __restrict__ dinv, unsigned short* __restrict__ h1s)
{
    __shared__ uint4 XAf[256];   // 4 m-tiles x 64 lanes, frag-contiguous
    const int tid  = threadIdx.x;
    const int wave = tid >> 6, lane = tid & 63;
    const int l16  = lane & 15, quad = lane >> 4;
    const int row0 = blockIdx.x * 64;

    f32x4 acc[4][2] = {};

    // staging: thread stages frag (t=wave, l=lane): row row0+wave*16+l16, k=quad*8
    int sr = row0 + wave * 16 + l16;
    if (sr >= N_NODES) sr = N_NODES - 1;
    const float* xrow = x + (size_t)sr * F_IN + (quad << 3);

    for (int c = 0; c < F_IN / 32; ++c) {
        float4 a = *(const float4*)(xrow + c * 32);
        float4 b = *(const float4*)(xrow + c * 32 + 4);
        uint4 fr;
        fr.x = pkbf(a.x, a.y); fr.y = pkbf(a.z, a.w);
        fr.z = pkbf(b.x, b.y); fr.w = pkbf(b.z, b.w);
        XAf[tid] = fr;
        __syncthreads();

        uint4 t0 = w1f[(size_t)(c * 8 + wave * 2 + 0) * 64 + lane];
        uint4 t1 = w1f[(size_t)(c * 8 + wave * 2 + 1) * 64 + lane];
        s16x8 bf0 = *(s16x8*)&t0, bf1 = *(s16x8*)&t1;

        #pragma unroll
        for (int i = 0; i < 4; ++i) {
            uint4 ta = XAf[i * 64 + lane];
            s16x8 af = *(s16x8*)&ta;
            acc[i][0] = __builtin_amdgcn_mfma_f32_16x16x32_bf16(af, bf0, acc[i][0], 0, 0, 0);
            acc[i][1] = __builtin_amdgcn_mfma_f32_16x16x32_bf16(af, bf1, acc[i][1], 0, 0, 0);
        }
        __syncthreads();
    }

    const int n0 = wave * 32;
    #pragma unroll
    for (int i = 0; i < 4; ++i) {
        #pragma unroll
        for (int p = 0; p < 4; ++p) {
            int gr = row0 + i * 16 + quad * 4 + p;
            if (gr < N_NODES) {
                float s = dinv[gr];
                #pragma unroll
                for (int u = 0; u < 2; ++u)
                    h1s[(size_t)gr * HIDDEN + n0 + u * 16 + l16] =
                        (unsigned short)bf16r(acc[i][u][p] * s);
            }
        }
    }
}

// ---------------- gather1: agg1(bf16) = relu(dinv[r]*(sum h1s[c] + h1s[r]) + b1)
__global__ __launch_bounds__(256) void gather1_kernel(
    const int* __restrict__ rowptr, const int* __restrict__ ecol,
    const float* __restrict__ dinv, const unsigned* __restrict__ h1u,
    const float* __restrict__ b1, unsigned* __restrict__ agg1u)
{
    const int wave = threadIdx.x >> 6, lane = threadIdx.x & 63;
    const int r = blockIdx.x * 4 + wave;
    if (r >= N_NODES) return;
    const int start = rowptr[r], end = rowptr[r + 1];

    float ax = 0.f, ay = 0.f, bx = 0.f, by = 0.f;
    float cx = 0.f, cy = 0.f, dx = 0.f, dy = 0.f;
    int e = start;
    for (; e + 3 < end; e += 4) {
        unsigned u0 = h1u[(size_t)ecol[e] * 64 + lane];
        unsigned u1 = h1u[(size_t)ecol[e + 1] * 64 + lane];
        unsigned u2 = h1u[(size_t)ecol[e + 2] * 64 + lane];
        unsigned u3 = h1u[(size_t)ecol[e + 3] * 64 + lane];
        ax += bflo(u0); ay += bfhi(u0); bx += bflo(u1); by += bfhi(u1);
        cx += bflo(u2); cy += bfhi(u2); dx += bflo(u3); dy += bfhi(u3);
    }
    for (; e < end; ++e) {
        unsigned u = h1u[(size_t)ecol[e] * 64 + lane];
        ax += bflo(u); ay += bfhi(u);
    }
    unsigned us = h1u[(size_t)r * 64 + lane];
    float sx = (ax + bx) + (cx + dx) + bflo(us);
    float sy = (ay + by) + (cy + dy) + bfhi(us);
    const float s = dinv[r];
    const float2 bb = *(const float2*)&b1[lane * 2];
    float ox = fmaxf(fmaf(s, sx, bb.x), 0.f);
    float oy = fmaxf(fmaf(s, sy, bb.y), 0.f);
    agg1u[(size_t)r * 64 + lane] = pkbf(ox, oy);
}

// ---------------- GEMM2 (MFMA): h2s[N,40]f32 = (agg1 @ W2) * dinv[row] -----
// block = 128 nodes x 48 cols (40 live), 4 waves; wave w owns m-tiles {2w,2w+1}
__global__ __launch_bounds__(256) void gemm2_kernel(
    const uint4* __restrict__ agg1q,  // bf16 rows: 16 uint4 per row
    const uint4* __restrict__ w2f,
    const float* __restrict__ dinv, float* __restrict__ h2s)
{
    __shared__ uint4 XAf[512];  // 8 m-tiles x 64 lanes
    const int tid  = threadIdx.x;
    const int wave = tid >> 6, lane = tid & 63;
    const int l16  = lane & 15, quad = lane >> 4;
    const int row0 = blockIdx.x * 128;

    f32x4 acc[2][3] = {};

    int r1 = row0 + wave * 16 + l16;        if (r1 >= N_NODES) r1 = N_NODES - 1;
    int r2 = row0 + (4 + wave) * 16 + l16;  if (r2 >= N_NODES) r2 = N_NODES - 1;

    for (int c = 0; c < 4; ++c) {
        XAf[tid]       = agg1q[(size_t)r1 * 16 + c * 4 + quad];
        XAf[tid + 256] = agg1q[(size_t)r2 * 16 + c * 4 + quad];
        __syncthreads();

        s16x8 bf[3];
        #pragma unroll
        for (int u = 0; u < 3; ++u) {
            uint4 t = w2f[(size_t)(c * 3 + u) * 64 + lane];
            bf[u] = *(s16x8*)&t;
        }
        #pragma unroll
        for (int i = 0; i < 2; ++i) {
            uint4 ta = XAf[(wave * 2 + i) * 64 + lane];
            s16x8 af = *(s16x8*)&ta;
            #pragma unroll
            for (int u = 0; u < 3; ++u)
                acc[i][u] = __builtin_amdgcn_mfma_f32_16x16x32_bf16(af, bf[u], acc[i][u], 0, 0, 0);
        }
        __syncthreads();
    }

    #pragma unroll
    for (int i = 0; i < 2; ++i) {
        #pragma unroll
        for (int p = 0; p < 4; ++p) {
            int gr = row0 + (wave * 2 + i) * 16 + quad * 4 + p;
            if (gr < N_NODES) {
                float s = dinv[gr];
                #pragma unroll
                for (int u = 0; u < 3; ++u) {
                    int ncol = u * 16 + l16;
                    if (ncol < N_CLASSES)
                        h2s[(size_t)gr * N_CLASSES + ncol] = acc[i][u][p] * s;
                }
            }
        }
    }
}

// ---------------- gather2: out = dinv[r]*(sum h2s[c] + h2s[r]) + b2 --------
__global__ __launch_bounds__(256) void gather2_kernel(
    const int* __restrict__ rowptr, const int* __restrict__ ecol,
    const float* __restrict__ dinv, const float* __restrict__ h2s,
    const float* __restrict__ b2, float* __restrict__ out)
{
    const int wave = threadIdx.x >> 6, lane = threadIdx.x & 63;
    const int r = blockIdx.x * 4 + wave;
    if (r >= N_NODES || lane >= N_CLASSES) return;
    const int start = rowptr[r], end = rowptr[r + 1];

    float a0 = 0.f, a1 = 0.f, a2 = 0.f, a3 = 0.f;
    int e = start;
    for (; e + 3 < end; e += 4) {
        a0 += h2s[(size_t)ecol[e] * N_CLASSES + lane];
        a1 += h2s[(size_t)ecol[e + 1] * N_CLASSES + lane];
        a2 += h2s[(size_t)ecol[e + 2] * N_CLASSES + lane];
        a3 += h2s[(size_t)ecol[e + 3] * N_CLASSES + lane];
    }
    for (; e < end; ++e) a0 += h2s[(size_t)ecol[e] * N_CLASSES + lane];
    float s = (a0 + a1) + (a2 + a3) + h2s[(size_t)r * N_CLASSES + lane];
    out[(size_t)r * N_CLASSES + lane] = fmaf(dinv[r], s, b2[lane]);
}

extern "C" void kernel_launch(void* const* d_in, const int* in_sizes, int n_in,
                              void* d_out, int out_size, void* d_ws, size_t ws_size,
                              hipStream_t stream)
{
    const float* x  = (const float*)d_in[0];
    const int*   ei = (const int*)d_in[1];
    const float* W1 = (const float*)d_in[2];
    const float* b1 = (const float*)d_in[3];
    const float* W2 = (const float*)d_in[4];
    const float* b2 = (const float*)d_in[5];
    const int* row = ei;            // destinations
    const int* col = ei + N_EDGES;  // sources

    float* ws = (float*)d_ws;
    int*   rowcnt   = (int*)(ws);                 // @0        (65536)
    int*   colcnt   = (int*)(ws + 65536);         // @65536    (65536)
    int*   cursor   = (int*)(ws + 131072);        // @131072   (65536)
    float* dinv     = ws + 196608;                // @196608   (65536)
    int*   rowptr   = (int*)(ws + 262144);        // @262144   (65536)
    int*   partials = (int*)(ws + 327680);        // @327680   (8192)
    int*   ecol     = (int*)(ws + 335872);        // @335872   (819200)
    uint4* w1f      = (uint4*)(ws + 1155072);     // 8192 frags (32768 floats)
    uint4* w2f      = (uint4*)(ws + 1187840);     // 768 frags  (3072 floats)
    unsigned short* h1s = (unsigned short*)(ws + 1190912);   // 50000*128 bf16
    unsigned*       h1u = (unsigned*)h1s;
    unsigned*  agg1u = (unsigned*)(ws + 4390912);            // 50000*128 bf16
    uint4*     agg1q = (uint4*)agg1u;
    float*     h2s   = ws + 7590912;                         // 50000*40 f32
    float*     out   = (float*)d_out;

    init_kernel<<<(N_NODES + 255) / 256, 256, 0, stream>>>(rowcnt, colcnt, cursor);
    count_kernel<<<(N_EDGES + 255) / 256, 256, 0, stream>>>(row, col, rowcnt, colcnt);
    deg_fin_kernel<<<(N_NODES + 255) / 256, 256, 0, stream>>>(colcnt, dinv);

    scan_blocks_kernel<<<NSCAN, 256, 0, stream>>>(rowcnt, rowptr, partials);
    scan_partials_kernel<<<1, 256, 0, stream>>>(partials);
    scan_add_kernel<<<NSCAN, 256, 0, stream>>>(rowptr, partials);
    place_kernel<<<(N_EDGES + 255) / 256, 256, 0, stream>>>(row, col, rowptr, cursor, ecol);

    w1frag_kernel<<<32, 256, 0, stream>>>(W1, w1f);
    w2frag_kernel<<<3, 256, 0, stream>>>(W2, w2f);

    gemm1_kernel<<<(N_NODES + 63) / 64, 256, 0, stream>>>(x, w1f, dinv, h1s);
    gather1_kernel<<<N_NODES / 4, 256, 0, stream>>>(rowptr, ecol, dinv, h1u, b1, agg1u);
    gemm2_kernel<<<(N_NODES + 127) / 128, 256, 0, stream>>>(agg1q, w2f, dinv, h2s);
    gather2_kernel<<<N_NODES / 4, 256, 0, stream>>>(rowptr, ecol, dinv, h2s, b2, out);
}

// Round 6
// 329.662 us; speedup vs baseline: 4.2233x; 1.1688x over previous
//
#include <hip/hip_runtime.h>
#include <hip/hip_bf16.h>

#define N_NODES 50000
#define N_EDGES 800000
#define F_IN 512
#define HIDDEN 128
#define N_CLASSES 40
#define NSCAN 196    // ceil(50000/256)

typedef __attribute__((ext_vector_type(4))) float f32x4;
typedef __attribute__((ext_vector_type(8))) short s16x8;

// manual RNE f32 -> bf16
__device__ __forceinline__ unsigned bf16r(float f) {
    unsigned u = __float_as_uint(f);
    return (u + 0x7fffu + ((u >> 16) & 1u)) >> 16;
}
__device__ __forceinline__ unsigned pkbf(float lo, float hi) {
    return bf16r(lo) | (bf16r(hi) << 16);
}
__device__ __forceinline__ float bflo(unsigned u) { return __uint_as_float(u << 16); }
__device__ __forceinline__ float bfhi(unsigned u) { return __uint_as_float(u & 0xffff0000u); }

// ---------------- prep: pack W1/W2 into MFMA B-fragment layout (bf16) ------
__global__ void prep_kernel(const float* __restrict__ W1, const float* __restrict__ W2,
                            uint4* __restrict__ w1f, uint4* __restrict__ w2f) {
    int f = blockIdx.x * 256 + threadIdx.x;
    if (f < 8192) {
        int lane = f & 63, u = (f >> 6) & 7, c = f >> 9;
        int k0 = c * 32 + ((lane >> 4) << 3), n = u * 16 + (lane & 15);
        float v[8];
        #pragma unroll
        for (int j = 0; j < 8; ++j) v[j] = W1[(size_t)(k0 + j) * HIDDEN + n];
        uint4 o;
        o.x = pkbf(v[0], v[1]); o.y = pkbf(v[2], v[3]);
        o.z = pkbf(v[4], v[5]); o.w = pkbf(v[6], v[7]);
        w1f[f] = o;
    } else if (f < 8960) {
        int g = f - 8192;
        int lane = g & 63, u = (g >> 6) % 3, c = g / 192;
        int k0 = c * 32 + ((lane >> 4) << 3), n = u * 16 + (lane & 15);
        float v[8];
        #pragma unroll
        for (int j = 0; j < 8; ++j)
            v[j] = (n < N_CLASSES) ? W2[(size_t)(k0 + j) * N_CLASSES + n] : 0.0f;
        uint4 o;
        o.x = pkbf(v[0], v[1]); o.y = pkbf(v[2], v[3]);
        o.z = pkbf(v[4], v[5]); o.w = pkbf(v[6], v[7]);
        w2f[g] = o;
    }
}

// ---------------- fused: GEMM1 (MFMA, unscaled) + edge count/pos -----------
// blockIdx%5==0 -> gemm block (782); else count block (3128).
__global__ __launch_bounds__(256) void fused_kernel(
    const float* __restrict__ x, const uint4* __restrict__ w1f,
    unsigned short* __restrict__ h1s,
    const int* __restrict__ row, const int* __restrict__ col,
    int* __restrict__ rowcnt, int* __restrict__ colcnt, int* __restrict__ pos8)
{
    __shared__ uint4 XAf[256];
    const int q = blockIdx.x / 5, rm = blockIdx.x % 5;

    if (rm != 0) {  // ---- count role ----
        const int cb = q * 4 + rm - 1;          // 0..3127
        const int e = cb * 256 + threadIdx.x;
        if (e < N_EDGES) {
            pos8[e] = atomicAdd(&rowcnt[row[e]], 1);
            atomicAdd(&colcnt[col[e]], 1);
        }
        return;
    }

    // ---- gemm role: 64 nodes x 128 feats ----
    const int tid  = threadIdx.x;
    const int wave = tid >> 6, lane = tid & 63;
    const int l16  = lane & 15, quad = lane >> 4;
    const int row0 = q * 64;

    f32x4 acc[4][2] = {};

    int sr = row0 + wave * 16 + l16;
    if (sr >= N_NODES) sr = N_NODES - 1;
    const float* xrow = x + (size_t)sr * F_IN + (quad << 3);

    for (int c = 0; c < F_IN / 32; ++c) {
        float4 a = *(const float4*)(xrow + c * 32);
        float4 b = *(const float4*)(xrow + c * 32 + 4);
        uint4 fr;
        fr.x = pkbf(a.x, a.y); fr.y = pkbf(a.z, a.w);
        fr.z = pkbf(b.x, b.y); fr.w = pkbf(b.z, b.w);
        XAf[tid] = fr;
        __syncthreads();

        uint4 t0 = w1f[(size_t)(c * 8 + wave * 2 + 0) * 64 + lane];
        uint4 t1 = w1f[(size_t)(c * 8 + wave * 2 + 1) * 64 + lane];
        s16x8 bf0 = *(s16x8*)&t0, bf1 = *(s16x8*)&t1;

        #pragma unroll
        for (int i = 0; i < 4; ++i) {
            uint4 ta = XAf[i * 64 + lane];
            s16x8 af = *(s16x8*)&ta;
            acc[i][0] = __builtin_amdgcn_mfma_f32_16x16x32_bf16(af, bf0, acc[i][0], 0, 0, 0);
            acc[i][1] = __builtin_amdgcn_mfma_f32_16x16x32_bf16(af, bf1, acc[i][1], 0, 0, 0);
        }
        __syncthreads();
    }

    const int n0 = wave * 32;
    #pragma unroll
    for (int i = 0; i < 4; ++i) {
        #pragma unroll
        for (int p = 0; p < 4; ++p) {
            int gr = row0 + i * 16 + quad * 4 + p;
            if (gr < N_NODES) {
                #pragma unroll
                for (int u = 0; u < 2; ++u)
                    h1s[(size_t)gr * HIDDEN + n0 + u * 16 + l16] =
                        (unsigned short)bf16r(acc[i][u][p]);
            }
        }
    }
}

// ---------------- scan of rowcnt -> rowptr, plus dinv from colcnt ----------
__global__ void scan_blocks_kernel(const int* __restrict__ rowcnt,
                                   const int* __restrict__ colcnt,
                                   float* __restrict__ dinv,
                                   int* __restrict__ rowptr, int* __restrict__ partials) {
    __shared__ int s[256];
    const int tid = threadIdx.x;
    const int i = blockIdx.x * 256 + tid;
    const int v = (i < N_NODES) ? rowcnt[i] : 0;
    s[tid] = v;
    __syncthreads();
    #pragma unroll
    for (int off = 1; off < 256; off <<= 1) {
        int t = (tid >= off) ? s[tid - off] : 0;
        __syncthreads();
        s[tid] += t;
        __syncthreads();
    }
    if (i < N_NODES) {
        rowptr[i] = s[tid] - v;
        dinv[i] = rsqrtf(1.0f + (float)colcnt[i]);  // +1 self-loop
    }
    if (tid == 255) partials[blockIdx.x] = s[255];
}

__global__ void scan_partials_kernel(int* __restrict__ partials) {
    __shared__ int s[256];
    const int tid = threadIdx.x;
    const int v = (tid < NSCAN) ? partials[tid] : 0;
    s[tid] = v;
    __syncthreads();
    #pragma unroll
    for (int off = 1; off < 256; off <<= 1) {
        int t = (tid >= off) ? s[tid - off] : 0;
        __syncthreads();
        s[tid] += t;
        __syncthreads();
    }
    if (tid < NSCAN) partials[tid] = s[tid] - v;
}

__global__ void scan_add_kernel(int* __restrict__ rowptr, const int* __restrict__ partials) {
    int i = blockIdx.x * 256 + threadIdx.x;
    if (i < N_NODES) rowptr[i] += partials[blockIdx.x];
    if (i == 0) rowptr[N_NODES] = N_EDGES;
}

// ---------------- CSR placement (no atomics) ----------------
__global__ void place_kernel(const int* __restrict__ row, const int* __restrict__ col,
                             const int* __restrict__ rowptr, const int* __restrict__ pos8,
                             int* __restrict__ ecol) {
    int e = blockIdx.x * 256 + threadIdx.x;
    if (e < N_EDGES) ecol[rowptr[row[e]] + pos8[e]] = col[e];
}

// ---- gather1: agg1(bf16) = relu(dinv[r]*(sum dinv[c]*h1[c] + dinv[r]*h1[r]) + b1)
__global__ __launch_bounds__(256) void gather1_kernel(
    const int* __restrict__ rowptr, const int* __restrict__ ecol,
    const float* __restrict__ dinv, const unsigned* __restrict__ h1u,
    const float* __restrict__ b1, unsigned* __restrict__ agg1u)
{
    const int wave = threadIdx.x >> 6, lane = threadIdx.x & 63;
    const int r = blockIdx.x * 4 + wave;
    if (r >= N_NODES) return;
    const int start = rowptr[r], end = rowptr[r + 1];

    float ax = 0.f, ay = 0.f, bx = 0.f, by = 0.f;
    float cx = 0.f, cy = 0.f, dx = 0.f, dy = 0.f;
    int e = start;
    for (; e + 3 < end; e += 4) {
        const int c0 = ecol[e], c1 = ecol[e + 1], c2 = ecol[e + 2], c3 = ecol[e + 3];
        const float d0 = dinv[c0], d1 = dinv[c1], d2 = dinv[c2], d3 = dinv[c3];
        unsigned u0 = h1u[(size_t)c0 * 64 + lane];
        unsigned u1 = h1u[(size_t)c1 * 64 + lane];
        unsigned u2 = h1u[(size_t)c2 * 64 + lane];
        unsigned u3 = h1u[(size_t)c3 * 64 + lane];
        ax = fmaf(bflo(u0), d0, ax); ay = fmaf(bfhi(u0), d0, ay);
        bx = fmaf(bflo(u1), d1, bx); by = fmaf(bfhi(u1), d1, by);
        cx = fmaf(bflo(u2), d2, cx); cy = fmaf(bfhi(u2), d2, cy);
        dx = fmaf(bflo(u3), d3, dx); dy = fmaf(bfhi(u3), d3, dy);
    }
    for (; e < end; ++e) {
        const int c = ecol[e];
        const float d = dinv[c];
        unsigned u = h1u[(size_t)c * 64 + lane];
        ax = fmaf(bflo(u), d, ax); ay = fmaf(bfhi(u), d, ay);
    }
    const float s = dinv[r];
    unsigned us = h1u[(size_t)r * 64 + lane];
    float sx = (ax + bx) + (cx + dx) + bflo(us) * s;
    float sy = (ay + by) + (cy + dy) + bfhi(us) * s;
    const float2 bb = *(const float2*)&b1[lane * 2];
    float ox = fmaxf(fmaf(s, sx, bb.x), 0.f);
    float oy = fmaxf(fmaf(s, sy, bb.y), 0.f);
    agg1u[(size_t)r * 64 + lane] = pkbf(ox, oy);
}

// ---------------- GEMM2 (MFMA): h2s[N,40]f32 = (agg1 @ W2) * dinv[row] -----
__global__ __launch_bounds__(256) void gemm2_kernel(
    const uint4* __restrict__ agg1q, const uint4* __restrict__ w2f,
    const float* __restrict__ dinv, float* __restrict__ h2s)
{
    __shared__ uint4 XAf[512];
    const int tid  = threadIdx.x;
    const int wave = tid >> 6, lane = tid & 63;
    const int l16  = lane & 15, quad = lane >> 4;
    const int row0 = blockIdx.x * 128;

    f32x4 acc[2][3] = {};

    int r1 = row0 + wave * 16 + l16;        if (r1 >= N_NODES) r1 = N_NODES - 1;
    int r2 = row0 + (4 + wave) * 16 + l16;  if (r2 >= N_NODES) r2 = N_NODES - 1;

    for (int c = 0; c < 4; ++c) {
        XAf[tid]       = agg1q[(size_t)r1 * 16 + c * 4 + quad];
        XAf[tid + 256] = agg1q[(size_t)r2 * 16 + c * 4 + quad];
        __syncthreads();

        s16x8 bf[3];
        #pragma unroll
        for (int u = 0; u < 3; ++u) {
            uint4 t = w2f[(size_t)(c * 3 + u) * 64 + lane];
            bf[u] = *(s16x8*)&t;
        }
        #pragma unroll
        for (int i = 0; i < 2; ++i) {
            uint4 ta = XAf[(wave * 2 + i) * 64 + lane];
            s16x8 af = *(s16x8*)&ta;
            #pragma unroll
            for (int u = 0; u < 3; ++u)
                acc[i][u] = __builtin_amdgcn_mfma_f32_16x16x32_bf16(af, bf[u], acc[i][u], 0, 0, 0);
        }
        __syncthreads();
    }

    #pragma unroll
    for (int i = 0; i < 2; ++i) {
        #pragma unroll
        for (int p = 0; p < 4; ++p) {
            int gr = row0 + (wave * 2 + i) * 16 + quad * 4 + p;
            if (gr < N_NODES) {
                float s = dinv[gr];
                #pragma unroll
                for (int u = 0; u < 3; ++u) {
                    int ncol = u * 16 + l16;
                    if (ncol < N_CLASSES)
                        h2s[(size_t)gr * N_CLASSES + ncol] = acc[i][u][p] * s;
                }
            }
        }
    }
}

// ---------------- gather2: out = dinv[r]*(sum h2s[c] + h2s[r]) + b2 --------
__global__ __launch_bounds__(256) void gather2_kernel(
    const int* __restrict__ rowptr, const int* __restrict__ ecol,
    const float* __restrict__ dinv, const float* __restrict__ h2s,
    const float* __restrict__ b2, float* __restrict__ out)
{
    const int wave = threadIdx.x >> 6, lane = threadIdx.x & 63;
    const int r = blockIdx.x * 4 + wave;
    if (r >= N_NODES || lane >= N_CLASSES) return;
    const int start = rowptr[r], end = rowptr[r + 1];

    float a0 = 0.f, a1 = 0.f, a2 = 0.f, a3 = 0.f;
    int e = start;
    for (; e + 3 < end; e += 4) {
        a0 += h2s[(size_t)ecol[e] * N_CLASSES + lane];
        a1 += h2s[(size_t)ecol[e + 1] * N_CLASSES + lane];
        a2 += h2s[(size_t)ecol[e + 2] * N_CLASSES + lane];
        a3 += h2s[(size_t)ecol[e + 3] * N_CLASSES + lane];
    }
    for (; e < end; ++e) a0 += h2s[(size_t)ecol[e] * N_CLASSES + lane];
    float s = (a0 + a1) + (a2 + a3) + h2s[(size_t)r * N_CLASSES + lane];
    out[(size_t)r * N_CLASSES + lane] = fmaf(dinv[r], s, b2[lane]);
}

extern "C" void kernel_launch(void* const* d_in, const int* in_sizes, int n_in,
                              void* d_out, int out_size, void* d_ws, size_t ws_size,
                              hipStream_t stream)
{
    const float* x  = (const float*)d_in[0];
    const int*   ei = (const int*)d_in[1];
    const float* W1 = (const float*)d_in[2];
    const float* b1 = (const float*)d_in[3];
    const float* W2 = (const float*)d_in[4];
    const float* b2 = (const float*)d_in[5];
    const int* row = ei;            // destinations
    const int* col = ei + N_EDGES;  // sources

    // ---- workspace layout, float-slot units (4 B each) ----
    // h1s   = 50000*128 bf16 = 6.4M elems = 3,200,000 float-slots
    // agg1u = 50000*64 uint  = 3,200,000 float-slots
    // h2s   = 50000*40 f32   = 2,000,000 float-slots
    float* ws = (float*)d_ws;
    int*   rowcnt   = (int*)(ws);                 // [0,        65536)   \ one memset
    int*   colcnt   = (int*)(ws + 65536);         // [65536,   131072)   /
    float* dinv     = ws + 131072;                // [131072,  196608)
    int*   rowptr   = (int*)(ws + 196608);        // [196608,  262144)  need 50001
    int*   partials = (int*)(ws + 262144);        // [262144,  270336)
    int*   pos8     = (int*)(ws + 270336);        // [270336, 1089536)
    int*   ecol     = (int*)(ws + 1089536);       // [1089536,1908736)
    uint4* w1f      = (uint4*)(ws + 1908736);     // [1908736,1941504)  8192 uint4
    uint4* w2f      = (uint4*)(ws + 1941504);     // [1941504,1944576)  768 uint4
    unsigned short* h1s = (unsigned short*)(ws + 1944576);  // [1944576,5144576)
    unsigned*       h1u = (unsigned*)h1s;
    unsigned* agg1u = (unsigned*)(ws + 5144576);            // [5144576,8344576)
    uint4*    agg1q = (uint4*)agg1u;
    float*    h2s   = ws + 8344576;                         // [8344576,10344576)
    float*    out   = (float*)d_out;

    hipMemsetAsync(rowcnt, 0, 2 * 65536 * sizeof(int), stream);
    prep_kernel<<<35, 256, 0, stream>>>(W1, W2, w1f, w2f);

    fused_kernel<<<3910, 256, 0, stream>>>(x, w1f, h1s, row, col, rowcnt, colcnt, pos8);

    scan_blocks_kernel<<<NSCAN, 256, 0, stream>>>(rowcnt, colcnt, dinv, rowptr, partials);
    scan_partials_kernel<<<1, 256, 0, stream>>>(partials);
    scan_add_kernel<<<NSCAN, 256, 0, stream>>>(rowptr, partials);
    place_kernel<<<3125, 256, 0, stream>>>(row, col, rowptr, pos8, ecol);

    gather1_kernel<<<N_NODES / 4, 256, 0, stream>>>(rowptr, ecol, dinv, h1u, b1, agg1u);
    gemm2_kernel<<<(N_NODES + 127) / 128, 256, 0, stream>>>(agg1q, w2f, dinv, h2s);
    gather2_kernel<<<N_NODES / 4, 256, 0, stream>>>(rowptr, ecol, dinv, h2s, b2, out);
}